// Round 9
// baseline (198.774 us; speedup 1.0000x reference)
//
#include <hip/hip_runtime.h>
#include <math.h>

typedef unsigned short ushort;
typedef unsigned int uint;
typedef __attribute__((ext_vector_type(8))) short bf16x8;
typedef __attribute__((ext_vector_type(4))) float f32x4;

constexpr int Bc  = 16;
constexpr float EPSc = 1e-5f;
constexpr float QSC  = 0.18033688f;  // 0.125 * log2(e): softmax exp -> exp2

__device__ inline ushort f2bf(float f) {
    uint u = __float_as_uint(f);
    uint r = (u + 0x7fffu + ((u >> 16) & 1u)) >> 16;
    return (ushort)r;
}
__device__ inline uint pack2(float a, float b) {
    return (uint)f2bf(a) | ((uint)f2bf(b) << 16);
}
// packed f32x2 -> bf16x2 (single v_cvt_pk_bf16_f32 on gfx950)
__device__ __forceinline__ uint cvt2(float a, float b) {
#if __has_builtin(__builtin_amdgcn_cvt_pk_bf16_f32)
    auto v = __builtin_amdgcn_cvt_pk_bf16_f32(a, b);
    uint u; __builtin_memcpy(&u, &v, 4); return u;
#else
    return pack2(a, b);
#endif
}
#if __has_builtin(__builtin_amdgcn_exp2f)
#define EXP2F(x) __builtin_amdgcn_exp2f(x)
#else
#define EXP2F(x) __expf((x) * 0.69314718f)
#endif

// ---------------------------------------------------------------------------
// K1: merged. Blocks 0..511: per-(b,g) partial sums (4 parts/group).
//     Blocks 512..767: weight convert; Q rows (<256) pre-scaled by QSC.
// ---------------------------------------------------------------------------
__global__ __launch_bounds__(256) void pre_k(
    const float* __restrict__ x, const float* __restrict__ qkvw,
    const float* __restrict__ pw, float* __restrict__ pstats,
    ushort* __restrict__ wqb, ushort* __restrict__ pwb) {
    int blk = blockIdx.x;
    if (blk < 512) {
        int bg = blk >> 2, part = blk & 3;
        const float4* p = (const float4*)(x + (size_t)bg * 32768 + part * 8192);
        float s = 0.f, s2 = 0.f;
        for (int i = threadIdx.x; i < 2048; i += 256) {
            float4 v = p[i];
            s += v.x + v.y + v.z + v.w;
            s2 += v.x*v.x + v.y*v.y + v.z*v.z + v.w*v.w;
        }
        __shared__ float rs[256], rq[256];
        rs[threadIdx.x] = s; rq[threadIdx.x] = s2;
        __syncthreads();
        for (int off = 128; off > 0; off >>= 1) {
            if (threadIdx.x < (unsigned)off) {
                rs[threadIdx.x] += rs[threadIdx.x + off];
                rq[threadIdx.x] += rq[threadIdx.x + off];
            }
            __syncthreads();
        }
        if (threadIdx.x == 0) {
            pstats[blk * 2]     = rs[0];
            pstats[blk * 2 + 1] = rq[0];
        }
    } else {
        int idx = ((blk - 512) * 256 + threadIdx.x) * 4;
        if (idx < 196608) {
            int row = idx >> 8;
            float sc = (row < 256) ? QSC : 1.f;
            float4 v = *(const float4*)&qkvw[idx];
            uint2 u; u.x = pack2(v.x * sc, v.y * sc); u.y = pack2(v.z * sc, v.w * sc);
            *(uint2*)&wqb[idx] = u;
        } else {
            int j = idx - 196608;
            float4 v = *(const float4*)&pw[j];
            uint2 u; u.x = pack2(v.x, v.y); u.y = pack2(v.z, v.w);
            *(uint2*)&pwb[j] = u;
        }
    }
}

// ---------------------------------------------------------------------------
// K2: GroupNorm (finalizing partial stats) + cast + transpose:
// x[b][c][n] -> xt[b][n][c] bf16. Grid (16, 4, 16).
// ---------------------------------------------------------------------------
__global__ __launch_bounds__(256) void norm_t_k(
    const float* __restrict__ x, const float* __restrict__ pstats,
    const float* __restrict__ nw, const float* __restrict__ nb,
    ushort* __restrict__ xt) {
    int b = blockIdx.z, ct = blockIdx.y, nt = blockIdx.x;
    __shared__ ushort T[64 * 72];
    int t = threadIdx.x;
    int nn4 = (t & 15) * 4;
#pragma unroll
    for (int p = 0; p < 4; ++p) {
        int cl = (t >> 4) + p * 16;
        int c = ct * 64 + cl;
        int g = c >> 5;
        int base = (b * 8 + g) * 8;
        float s  = (pstats[base] + pstats[base+2]) + (pstats[base+4] + pstats[base+6]);
        float s2 = (pstats[base+1] + pstats[base+3]) + (pstats[base+5] + pstats[base+7]);
        float inv_n = 1.f / 32768.f;
        float mean = s * inv_n;
        float var  = s2 * inv_n - mean * mean;
        float inv  = rsqrtf(var + EPSc);
        float sw = inv * nw[c];
        float sb = nb[c] - mean * sw;
        float4 v = *(const float4*)&x[((size_t)(b * 256 + c)) * 1024 + nt * 64 + nn4];
        T[(nn4 + 0) * 72 + cl] = f2bf(v.x * sw + sb);
        T[(nn4 + 1) * 72 + cl] = f2bf(v.y * sw + sb);
        T[(nn4 + 2) * 72 + cl] = f2bf(v.z * sw + sb);
        T[(nn4 + 3) * 72 + cl] = f2bf(v.w * sw + sb);
    }
    __syncthreads();
#pragma unroll
    for (int p = 0; p < 4; ++p) {
        int nn = (t >> 4) + p * 16;
        int c4 = (t & 15) * 4;
        uint2 w = *(const uint2*)&T[nn * 72 + c4];
        *(uint2*)&xt[((size_t)b * 1024 + nt * 64 + nn) * 256 + ct * 64 + c4] = w;
    }
}

// ---------------------------------------------------------------------------
// K3: qkv GEMM, bf16 MFMA, NO LDS STAGING / NO BARRIERS: A and B fragments
// load directly from global (both are row-major k-contiguous = MFMA layout).
// Compiler pipelines with fine vmcnt; W re-reads hit L2 (128 blocks share),
// X re-reads hit L1/L2. 128x128 tile, 8 k-slabs of 32, 16 MFMA/slab.
// chan-tiles 0..3 (Q,K): transposed out qkT[b][sp][512] (Q pre-scaled QSC).
// chan-tiles 4..5 (V): natural out vbuf[b][chan][sp].
// Wave-private LDS transpose epilogue (no barrier).
// ---------------------------------------------------------------------------
__global__ __launch_bounds__(256, 3) void qkv_gemm_k(
    const ushort* __restrict__ wq, const ushort* __restrict__ xt,
    const float* __restrict__ wb, ushort* __restrict__ qkT,
    ushort* __restrict__ vbuf) {
    int b = blockIdx.z, cy = blockIdx.y, sx = blockIdx.x;
    __shared__ ushort POOL[4 * 64 * 72];  // epilogue transpose only (36.9KB)
    int t = threadIdx.x, lane = t & 63, w = t >> 6;
    int quad = lane >> 4, l15 = lane & 15;
    int wm = w >> 1, wn = w & 1;
    bool tpath = (cy < 4);
    const ushort* wrow = wq + (size_t)cy * 128 * 256;
    const ushort* xrow = xt + ((size_t)b * 1024 + sx * 128) * 256;
    const ushort* arow = tpath ? xrow : wrow;   // A = m-operand rows
    const ushort* brow = tpath ? wrow : xrow;   // B = n-operand rows
    f32x4 acc[4][4] = {};
#pragma unroll 2
    for (int ks = 0; ks < 8; ++ks) {
        int k0 = ks * 32 + quad * 8;
        bf16x8 fa[4], fb[4];
#pragma unroll
        for (int mi = 0; mi < 4; ++mi)
            fa[mi] = *(const bf16x8*)&arow[(size_t)(wm * 64 + mi * 16 + l15) * 256 + k0];
#pragma unroll
        for (int ni = 0; ni < 4; ++ni)
            fb[ni] = *(const bf16x8*)&brow[(size_t)(wn * 64 + ni * 16 + l15) * 256 + k0];
#pragma unroll
        for (int mi = 0; mi < 4; ++mi)
#pragma unroll
            for (int ni = 0; ni < 4; ++ni)
                acc[mi][ni] = __builtin_amdgcn_mfma_f32_16x16x32_bf16(
                    fa[mi], fb[ni], acc[mi][ni], 0, 0, 0);
    }
    // ---- epilogue: wave-private 64x64 LDS transpose (stride 72), uint4 stores
    ushort* Tw = POOL + w * (64 * 72);
    float bsc = (tpath && cy < 2) ? QSC : 1.f;
    if (tpath) {
#pragma unroll
        for (int ni = 0; ni < 4; ++ni) {
            float bias = wb[cy * 128 + wn * 64 + ni * 16 + l15] * bsc;
#pragma unroll
            for (int mi = 0; mi < 4; ++mi)
#pragma unroll
                for (int rr = 0; rr < 4; ++rr)
                    Tw[(mi * 16 + quad * 4 + rr) * 72 + ni * 16 + l15] =
                        f2bf(acc[mi][ni][rr] + bias);
        }
    } else {
#pragma unroll
        for (int mi = 0; mi < 4; ++mi)
#pragma unroll
            for (int rr = 0; rr < 4; ++rr) {
                float bias = wb[cy * 128 + wm * 64 + mi * 16 + quad * 4 + rr];
#pragma unroll
                for (int ni = 0; ni < 4; ++ni)
                    Tw[(mi * 16 + quad * 4 + rr) * 72 + ni * 16 + l15] =
                        f2bf(acc[mi][ni][rr] + bias);
            }
    }
    __asm__ __volatile__("" ::: "memory");  // wave-private region; DS in-order
    int row8 = lane >> 3, ch = lane & 7;
#pragma unroll
    for (int p = 0; p < 8; ++p) {
        int row = p * 8 + row8;
        uint4 u = *(const uint4*)&Tw[row * 72 + ch * 8];
        if (tpath) {
            int sp = sx * 128 + wm * 64 + row;
            *(uint4*)&qkT[((size_t)b * 1024 + sp) * 512 + cy * 128 + wn * 64 + ch * 8] = u;
        } else {
            int chanloc = (cy - 4) * 128 + wm * 64 + row;
            *(uint4*)&vbuf[((size_t)b * 256 + chanloc) * 1024 + sx * 128 + wn * 64 + ch * 8] = u;
        }
    }
}

// ---------------------------------------------------------------------------
// K4: flash attention, 128-row i-tiles, NO LDS STAGING / NO BARRIERS.
// K/V fragments load directly from global (qkT rows / vbuf rows are in MFMA
// fragment layout); 4 waves' re-reads of the same 8KB tiles hit L1.
// Wave-private Ps round-trip (C->A layout) and Lx only. Grid (8, 64).
// ---------------------------------------------------------------------------
__global__ __launch_bounds__(256, 3) void attn_k(
    const ushort* __restrict__ qkT, const ushort* __restrict__ vbuf,
    ushort* __restrict__ ot) {
    int i0 = blockIdx.x * 128;
    int bh = blockIdx.y;
    int b = bh >> 2, h = bh & 3;
    const ushort* qTb = qkT + (size_t)b * 1024 * 512 + h * 64;
    const ushort* kTb = qTb + 256;
    const ushort* vb  = vbuf + ((size_t)(b * 256 + h * 64)) * 1024;
    __shared__ ushort Ps[8 * 1152];   // [wave][rb] 16x64 pad 72
    __shared__ float  Lx[128];
    int t = threadIdx.x, lane = t & 63, w = t >> 6;
    int quad = lane >> 4, l15 = lane & 15;
    bf16x8 aq[2][2];
#pragma unroll
    for (int rb = 0; rb < 2; ++rb) {
        const ushort* qr = &qTb[(size_t)(i0 + rb * 64 + w * 16 + l15) * 512];
        aq[rb][0] = *(const bf16x8*)&qr[quad * 8];
        aq[rb][1] = *(const bf16x8*)&qr[32 + quad * 8];
    }
    float lsum0 = 0.f, lsum1 = 0.f;
    f32x4 oacc[2][4] = {};
    ushort* Pw0 = &Ps[(w * 2 + 0) * 1152];
    ushort* Pw1 = &Ps[(w * 2 + 1) * 1152];
    for (int j0 = 0; j0 < 1024; j0 += 64) {
        // ---- S^T: K fragments direct from global, shared by both row-blocks
        f32x4 s0[4], s1[4];
#pragma unroll
        for (int jt = 0; jt < 4; ++jt) {
            const ushort* kr = &kTb[(size_t)(j0 + jt * 16 + l15) * 512];
            bf16x8 bk0 = *(const bf16x8*)&kr[quad * 8];
            bf16x8 bk1 = *(const bf16x8*)&kr[32 + quad * 8];
            f32x4 a = {0.f, 0.f, 0.f, 0.f};
            a = __builtin_amdgcn_mfma_f32_16x16x32_bf16(bk0, aq[0][0], a, 0, 0, 0);
            a = __builtin_amdgcn_mfma_f32_16x16x32_bf16(bk1, aq[0][1], a, 0, 0, 0);
            s0[jt] = a;
            f32x4 c = {0.f, 0.f, 0.f, 0.f};
            c = __builtin_amdgcn_mfma_f32_16x16x32_bf16(bk0, aq[1][0], c, 0, 0, 0);
            c = __builtin_amdgcn_mfma_f32_16x16x32_bf16(bk1, aq[1][1], c, 0, 0, 0);
            s1[jt] = c;
        }
        // ---- p = 2^s (scale pre-folded), packed cvt, thread-local l ----
#pragma unroll
        for (int jt = 0; jt < 4; ++jt) {
            int o = l15 * 72 + jt * 16 + quad * 4;
            float e0 = EXP2F(s0[jt][0]), e1 = EXP2F(s0[jt][1]);
            float e2 = EXP2F(s0[jt][2]), e3 = EXP2F(s0[jt][3]);
            lsum0 += (e0 + e1) + (e2 + e3);
            *(uint*)&Pw0[o]     = cvt2(e0, e1);
            *(uint*)&Pw0[o + 2] = cvt2(e2, e3);
            float f0 = EXP2F(s1[jt][0]), f1 = EXP2F(s1[jt][1]);
            float f2 = EXP2F(s1[jt][2]), f3 = EXP2F(s1[jt][3]);
            lsum1 += (f0 + f1) + (f2 + f3);
            *(uint*)&Pw1[o]     = cvt2(f0, f1);
            *(uint*)&Pw1[o + 2] = cvt2(f2, f3);
        }
        __asm__ __volatile__("" ::: "memory");  // wave-private Ps; DS in-order
        bf16x8 ap00 = *(const bf16x8*)&Pw0[l15 * 72 + quad * 8];
        bf16x8 ap01 = *(const bf16x8*)&Pw0[l15 * 72 + 32 + quad * 8];
        bf16x8 ap10 = *(const bf16x8*)&Pw1[l15 * 72 + quad * 8];
        bf16x8 ap11 = *(const bf16x8*)&Pw1[l15 * 72 + 32 + quad * 8];
        // ---- O += P V: V fragments direct from global, shared by both rbs
#pragma unroll
        for (int ct = 0; ct < 4; ++ct) {
            const ushort* vr = &vb[(size_t)(ct * 16 + l15) * 1024 + j0];
            bf16x8 bv0 = *(const bf16x8*)&vr[quad * 8];
            bf16x8 bv1 = *(const bf16x8*)&vr[32 + quad * 8];
            oacc[0][ct] = __builtin_amdgcn_mfma_f32_16x16x32_bf16(ap00, bv0, oacc[0][ct], 0, 0, 0);
            oacc[0][ct] = __builtin_amdgcn_mfma_f32_16x16x32_bf16(ap01, bv1, oacc[0][ct], 0, 0, 0);
            oacc[1][ct] = __builtin_amdgcn_mfma_f32_16x16x32_bf16(ap10, bv0, oacc[1][ct], 0, 0, 0);
            oacc[1][ct] = __builtin_amdgcn_mfma_f32_16x16x32_bf16(ap11, bv1, oacc[1][ct], 0, 0, 0);
        }
    }
    // ---- l reductions (per rb): sum across quads for row i = w*16+l15 ----
    lsum0 += __shfl_xor(lsum0, 16); lsum0 += __shfl_xor(lsum0, 32);
    lsum1 += __shfl_xor(lsum1, 16); lsum1 += __shfl_xor(lsum1, 32);
    if (quad == 0) {
        Lx[w * 16 + l15]      = lsum0;
        Lx[64 + w * 16 + l15] = lsum1;
    }
    __asm__ __volatile__("" ::: "memory");
#pragma unroll
    for (int rb = 0; rb < 2; ++rb) {
        float4 lv = *(const float4*)&Lx[rb * 64 + w * 16 + quad * 4];
        float linv[4] = {1.f / lv.x, 1.f / lv.y, 1.f / lv.z, 1.f / lv.w};
        ushort* Pw = (rb == 0) ? Pw0 : Pw1;
#pragma unroll
        for (int ct = 0; ct < 4; ++ct)
#pragma unroll
            for (int rr = 0; rr < 4; ++rr)
                Pw[(quad * 4 + rr) * 72 + ct * 16 + l15] = f2bf(oacc[rb][ct][rr] * linv[rr]);
        __asm__ __volatile__("" ::: "memory");
#pragma unroll
        for (int p = 0; p < 2; ++p) {
            int row = p * 8 + (lane >> 3), ch = lane & 7;
            uint4 u = *(const uint4*)&Pw[row * 72 + ch * 8];
            *(uint4*)&ot[((size_t)b * 1024 + i0 + rb * 64 + w * 16 + row) * 256 + h * 64 + ch * 8] = u;
        }
    }
}

// ---------------------------------------------------------------------------
// K5: proj GEMM + bias + residual, fp32 out. NO LDS / NO BARRIERS:
// direct-fragment loads like K3. Grid (8, 2, 16).
// ---------------------------------------------------------------------------
__global__ __launch_bounds__(256, 3) void proj_k(
    const ushort* __restrict__ pwb, const ushort* __restrict__ ot,
    const float* __restrict__ pb, const float* __restrict__ x,
    float* __restrict__ out) {
    int b = blockIdx.z, cy = blockIdx.y, sx = blockIdx.x;
    int t = threadIdx.x, lane = t & 63, w = t >> 6;
    int quad = lane >> 4, l15 = lane & 15;
    int wm = w >> 1, wn = w & 1;
    const ushort* wrow = pwb + (size_t)cy * 128 * 256;
    const ushort* xrow = ot + ((size_t)b * 1024 + sx * 128) * 256;
    f32x4 acc[4][4] = {};
#pragma unroll 2
    for (int ks = 0; ks < 8; ++ks) {
        int k0 = ks * 32 + quad * 8;
        bf16x8 fa[4], fb[4];
#pragma unroll
        for (int mi = 0; mi < 4; ++mi)
            fa[mi] = *(const bf16x8*)&wrow[(size_t)(wm * 64 + mi * 16 + l15) * 256 + k0];
#pragma unroll
        for (int ni = 0; ni < 4; ++ni)
            fb[ni] = *(const bf16x8*)&xrow[(size_t)(wn * 64 + ni * 16 + l15) * 256 + k0];
#pragma unroll
        for (int mi = 0; mi < 4; ++mi)
#pragma unroll
            for (int ni = 0; ni < 4; ++ni)
                acc[mi][ni] = __builtin_amdgcn_mfma_f32_16x16x32_bf16(
                    fa[mi], fb[ni], acc[mi][ni], 0, 0, 0);
    }
#pragma unroll
    for (int mi = 0; mi < 4; ++mi)
#pragma unroll
        for (int rr = 0; rr < 4; ++rr) {
            int chan = cy * 128 + wm * 64 + mi * 16 + quad * 4 + rr;
            float bias = pb[chan];
#pragma unroll
            for (int ni = 0; ni < 4; ++ni) {
                int sp = sx * 128 + wn * 64 + ni * 16 + l15;
                size_t o = ((size_t)(b * 256 + chan)) * 1024 + sp;
                out[o] = acc[mi][ni][rr] + bias + x[o];
            }
        }
}

// ---------------------------------------------------------------------------
extern "C" void kernel_launch(void* const* d_in, const int* in_sizes, int n_in,
                              void* d_out, int out_size, void* d_ws, size_t ws_size,
                              hipStream_t stream) {
    const float* x    = (const float*)d_in[0];
    const float* nw   = (const float*)d_in[1];
    const float* nb   = (const float*)d_in[2];
    const float* qkvw = (const float*)d_in[3];
    const float* qkvb = (const float*)d_in[4];
    const float* pw   = (const float*)d_in[5];
    const float* pb   = (const float*)d_in[6];
    float* out = (float*)d_out;

    // Workspace: pstats(1024 f32) | xt | wqb | pwb | qkT | vbuf  (~34 MB)
    // ot ALIASES xt (xt's last reader precedes ot's first writer).
    float* pstats = (float*)d_ws;
    ushort* base = (ushort*)((char*)d_ws + 4096);
    ushort* xt   = base;                          // 16*1024*256
    ushort* wqb  = xt + (size_t)16 * 1024 * 256;  // 768*256
    ushort* pwb  = wqb + 768 * 256;               // 256*256
    ushort* qkT  = pwb + 256 * 256;               // 16*1024*512
    ushort* vbuf = qkT + (size_t)16 * 1024 * 512; // 16*256*1024
    ushort* ot   = xt;                            // reuse

    pre_k<<<dim3(768), dim3(256), 0, stream>>>(x, qkvw, pw, pstats, wqb, pwb);
    norm_t_k<<<dim3(16, 4, Bc), dim3(256), 0, stream>>>(x, pstats, nw, nb, xt);
    qkv_gemm_k<<<dim3(8, 6, Bc), dim3(256), 0, stream>>>(wqb, xt, qkvb, qkT, vbuf);
    attn_k<<<dim3(8, 64), dim3(256), 0, stream>>>(qkT, vbuf, ot);
    proj_k<<<dim3(8, 2, Bc), dim3(256), 0, stream>>>(pwb, ot, pb, x, out);
}

// Round 10
// 143.245 us; speedup vs baseline: 1.3876x; 1.3876x over previous
//
#include <hip/hip_runtime.h>
#include <math.h>

typedef unsigned short ushort;
typedef unsigned int uint;
typedef __attribute__((ext_vector_type(8))) short bf16x8;
typedef __attribute__((ext_vector_type(4))) float f32x4;

constexpr int Bc  = 16;
constexpr float EPSc = 1e-5f;
constexpr float QSC  = 0.18033688f;  // 0.125 * log2(e): softmax exp -> exp2

__device__ inline ushort f2bf(float f) {
    uint u = __float_as_uint(f);
    uint r = (u + 0x7fffu + ((u >> 16) & 1u)) >> 16;
    return (ushort)r;
}
__device__ inline uint pack2(float a, float b) {
    return (uint)f2bf(a) | ((uint)f2bf(b) << 16);
}
__device__ __forceinline__ uint cvt2(float a, float b) {
#if __has_builtin(__builtin_amdgcn_cvt_pk_bf16_f32)
    auto v = __builtin_amdgcn_cvt_pk_bf16_f32(a, b);
    uint u; __builtin_memcpy(&u, &v, 4); return u;
#else
    return pack2(a, b);
#endif
}
#if __has_builtin(__builtin_amdgcn_exp2f)
#define EXP2F(x) __builtin_amdgcn_exp2f(x)
#else
#define EXP2F(x) __expf((x) * 0.69314718f)
#endif
__device__ __forceinline__ void gl_lds16(const ushort* g, ushort* l) {
    __builtin_amdgcn_global_load_lds(
        (const __attribute__((address_space(1))) void*)g,
        (__attribute__((address_space(3))) void*)l, 16, 0, 0);
}
__device__ __forceinline__ float bfl(uint u) { return __uint_as_float(u << 16); }
__device__ __forceinline__ float bfh(uint u) { return __uint_as_float(u & 0xffff0000u); }

// ---------------------------------------------------------------------------
// K1: merged. Blocks 0..511: per-(b,g) partial sums. 512..767: weight cvt.
// ---------------------------------------------------------------------------
__global__ __launch_bounds__(256) void pre_k(
    const float* __restrict__ x, const float* __restrict__ qkvw,
    const float* __restrict__ pw, float* __restrict__ pstats,
    ushort* __restrict__ wqb, ushort* __restrict__ pwb) {
    int blk = blockIdx.x;
    if (blk < 512) {
        int bg = blk >> 2, part = blk & 3;
        const float4* p = (const float4*)(x + (size_t)bg * 32768 + part * 8192);
        float s = 0.f, s2 = 0.f;
        for (int i = threadIdx.x; i < 2048; i += 256) {
            float4 v = p[i];
            s += v.x + v.y + v.z + v.w;
            s2 += v.x*v.x + v.y*v.y + v.z*v.z + v.w*v.w;
        }
        __shared__ float rs[256], rq[256];
        rs[threadIdx.x] = s; rq[threadIdx.x] = s2;
        __syncthreads();
        for (int off = 128; off > 0; off >>= 1) {
            if (threadIdx.x < (unsigned)off) {
                rs[threadIdx.x] += rs[threadIdx.x + off];
                rq[threadIdx.x] += rq[threadIdx.x + off];
            }
            __syncthreads();
        }
        if (threadIdx.x == 0) {
            pstats[blk * 2]     = rs[0];
            pstats[blk * 2 + 1] = rq[0];
        }
    } else {
        int idx = ((blk - 512) * 256 + threadIdx.x) * 4;
        if (idx < 196608) {
            int row = idx >> 8;
            float sc = (row < 256) ? QSC : 1.f;
            float4 v = *(const float4*)&qkvw[idx];
            uint2 u; u.x = pack2(v.x * sc, v.y * sc); u.y = pack2(v.z * sc, v.w * sc);
            *(uint2*)&wqb[idx] = u;
        } else {
            int j = idx - 196608;
            float4 v = *(const float4*)&pw[j];
            uint2 u; u.x = pack2(v.x, v.y); u.y = pack2(v.z, v.w);
            *(uint2*)&pwb[j] = u;
        }
    }
}

// ---------------------------------------------------------------------------
// K2: GroupNorm + cast + transpose: x[b][c][n] -> xt[b][n][c]. Grid (16,4,16).
// ---------------------------------------------------------------------------
__global__ __launch_bounds__(256) void norm_t_k(
    const float* __restrict__ x, const float* __restrict__ pstats,
    const float* __restrict__ nw, const float* __restrict__ nb,
    ushort* __restrict__ xt) {
    int b = blockIdx.z, ct = blockIdx.y, nt = blockIdx.x;
    __shared__ ushort T[64 * 72];
    int t = threadIdx.x;
    int nn4 = (t & 15) * 4;
#pragma unroll
    for (int p = 0; p < 4; ++p) {
        int cl = (t >> 4) + p * 16;
        int c = ct * 64 + cl;
        int g = c >> 5;
        int base = (b * 8 + g) * 8;
        float s  = (pstats[base] + pstats[base+2]) + (pstats[base+4] + pstats[base+6]);
        float s2 = (pstats[base+1] + pstats[base+3]) + (pstats[base+5] + pstats[base+7]);
        float inv_n = 1.f / 32768.f;
        float mean = s * inv_n;
        float var  = s2 * inv_n - mean * mean;
        float inv  = rsqrtf(var + EPSc);
        float sw = inv * nw[c];
        float sb = nb[c] - mean * sw;
        float4 v = *(const float4*)&x[((size_t)(b * 256 + c)) * 1024 + nt * 64 + nn4];
        T[(nn4 + 0) * 72 + cl] = f2bf(v.x * sw + sb);
        T[(nn4 + 1) * 72 + cl] = f2bf(v.y * sw + sb);
        T[(nn4 + 2) * 72 + cl] = f2bf(v.z * sw + sb);
        T[(nn4 + 3) * 72 + cl] = f2bf(v.w * sw + sb);
    }
    __syncthreads();
#pragma unroll
    for (int p = 0; p < 4; ++p) {
        int nn = (t >> 4) + p * 16;
        int c4 = (t & 15) * 4;
        uint2 w = *(const uint2*)&T[nn * 72 + c4];
        *(uint2*)&xt[((size_t)b * 1024 + nt * 64 + nn) * 256 + ct * 64 + c4] = w;
    }
}

// ---------------------------------------------------------------------------
// K3: qkv GEMM (round-7 proven): BK=64 async dbuf, 1 barrier/iter.
// 128x128 tile, 4 waves. cy 0..3 -> qkT transposed; cy 4..5 -> vbuf natural.
// ---------------------------------------------------------------------------
__global__ __launch_bounds__(256, 2) void qkv_gemm_k(
    const ushort* __restrict__ wq, const ushort* __restrict__ xt,
    const float* __restrict__ wb, ushort* __restrict__ qkT,
    ushort* __restrict__ vbuf) {
    int b = blockIdx.z, cy = blockIdx.y, sx = blockIdx.x;
    __shared__ ushort SB[2][2][128 * 64];
    int t = threadIdx.x, lane = t & 63, w = t >> 6;
    int quad = lane >> 4, l15 = lane & 15;
    int wm = w >> 1, wn = w & 1;
    const ushort* wrow = wq + (size_t)cy * 128 * 256;
    const ushort* xrow = xt + ((size_t)b * 1024 + sx * 128) * 256;
    bool tpath = (cy < 4);
    int r0 = t >> 3;
    int cs = (t & 7) ^ (r0 & 7);
    int dst = t * 8;
#pragma unroll
    for (int ps = 0; ps < 4; ++ps) {
        int r = r0 + ps * 32;
        gl_lds16(&wrow[(size_t)r * 256 + cs * 8], &SB[0][0][ps * 2048 + dst]);
        gl_lds16(&xrow[(size_t)r * 256 + cs * 8], &SB[0][1][ps * 2048 + dst]);
    }
    __syncthreads();
    int s0 = quad ^ (l15 & 7);
    f32x4 acc[4][4] = {};
    int cur = 0;
    for (int ki = 0; ki < 4; ++ki) {
        if (ki < 3) {
            int k0 = (ki + 1) * 64, nx = cur ^ 1;
#pragma unroll
            for (int ps = 0; ps < 4; ++ps) {
                int r = r0 + ps * 32;
                gl_lds16(&wrow[(size_t)r * 256 + k0 + cs * 8], &SB[nx][0][ps * 2048 + dst]);
                gl_lds16(&xrow[(size_t)r * 256 + k0 + cs * 8], &SB[nx][1][ps * 2048 + dst]);
            }
        }
        const ushort* Wc = SB[cur][0];
        const ushort* Xc = SB[cur][1];
        const ushort* Am = tpath ? Xc : Wc;
        const ushort* Bn = tpath ? Wc : Xc;
#pragma unroll
        for (int kk = 0; kk < 2; ++kk) {
            int sl = s0 ^ (kk * 4);
            bf16x8 fa[4], fb[4];
#pragma unroll
            for (int mi = 0; mi < 4; ++mi)
                fa[mi] = *(const bf16x8*)&Am[(wm * 64 + mi * 16 + l15) * 64 + sl * 8];
#pragma unroll
            for (int ni = 0; ni < 4; ++ni)
                fb[ni] = *(const bf16x8*)&Bn[(wn * 64 + ni * 16 + l15) * 64 + sl * 8];
#pragma unroll
            for (int mi = 0; mi < 4; ++mi)
#pragma unroll
                for (int ni = 0; ni < 4; ++ni)
                    acc[mi][ni] = __builtin_amdgcn_mfma_f32_16x16x32_bf16(
                        fa[mi], fb[ni], acc[mi][ni], 0, 0, 0);
        }
        __syncthreads();
        cur ^= 1;
    }
    __syncthreads();
    ushort* Tw = ((ushort*)SB) + w * (64 * 72);
    float bsc = (tpath && cy < 2) ? QSC : 1.f;
    if (tpath) {
#pragma unroll
        for (int ni = 0; ni < 4; ++ni) {
            float bias = wb[cy * 128 + wn * 64 + ni * 16 + l15] * bsc;
#pragma unroll
            for (int mi = 0; mi < 4; ++mi)
#pragma unroll
                for (int rr = 0; rr < 4; ++rr)
                    Tw[(mi * 16 + quad * 4 + rr) * 72 + ni * 16 + l15] =
                        f2bf(acc[mi][ni][rr] + bias);
        }
    } else {
#pragma unroll
        for (int mi = 0; mi < 4; ++mi)
#pragma unroll
            for (int rr = 0; rr < 4; ++rr) {
                float bias = wb[cy * 128 + wm * 64 + mi * 16 + quad * 4 + rr];
#pragma unroll
                for (int ni = 0; ni < 4; ++ni)
                    Tw[(mi * 16 + quad * 4 + rr) * 72 + ni * 16 + l15] =
                        f2bf(acc[mi][ni][rr] + bias);
            }
    }
    __asm__ __volatile__("" ::: "memory");
    int row8 = lane >> 3, ch = lane & 7;
#pragma unroll
    for (int p = 0; p < 8; ++p) {
        int row = p * 8 + row8;
        uint4 u = *(const uint4*)&Tw[row * 72 + ch * 8];
        if (tpath) {
            int sp = sx * 128 + wm * 64 + row;
            *(uint4*)&qkT[((size_t)b * 1024 + sp) * 512 + cy * 128 + wn * 64 + ch * 8] = u;
        } else {
            int chanloc = (cy - 4) * 128 + wm * 64 + row;
            *(uint4*)&vbuf[((size_t)b * 256 + chanloc) * 1024 + sx * 128 + wn * 64 + ch * 8] = u;
        }
    }
}

// ---------------------------------------------------------------------------
// K4: flash attention, 128-row i-tiles, j-SPLIT across blockIdx.z (2 halves
// of 512 j each -> 8 iters/block, halved critical path). Writes UNNORMALIZED
// partial O (bf16) + per-row l (f32); comb_k merges. Grid (8, 64, 2).
// ---------------------------------------------------------------------------
__global__ __launch_bounds__(256, 3) void attn_k(
    const ushort* __restrict__ qkT, const ushort* __restrict__ vbuf,
    ushort* __restrict__ op0, ushort* __restrict__ op1,
    float* __restrict__ lpart) {
    int i0 = blockIdx.x * 128;
    int bh = blockIdx.y;
    int jz = blockIdx.z;
    int b = bh >> 2, h = bh & 3;
    const ushort* qTb = qkT + (size_t)b * 1024 * 512 + h * 64;
    const ushort* kTb = qTb + 256 + (size_t)jz * 512 * 512;
    const ushort* vb  = vbuf + ((size_t)(b * 256 + h * 64)) * 1024 + jz * 512;
    ushort* opart = jz ? op1 : op0;
    float* lp = lpart + jz * 65536 + bh * 1024;
    __shared__ ushort Ks[2][4096], Vs[2][4096];
    __shared__ ushort Ps[8 * 1152];
    int t = threadIdx.x, lane = t & 63, w = t >> 6;
    int quad = lane >> 4, l15 = lane & 15;
    bf16x8 aq[2][2];
#pragma unroll
    for (int rb = 0; rb < 2; ++rb) {
        const ushort* qr = &qTb[(size_t)(i0 + rb * 64 + w * 16 + l15) * 512];
        aq[rb][0] = *(const bf16x8*)&qr[quad * 8];
        aq[rb][1] = *(const bf16x8*)&qr[32 + quad * 8];
    }
    int r0 = t >> 3;
    int cs = (t & 7) ^ (r0 & 7);
    int p0 = quad ^ (l15 & 7);
    int p1 = p0 ^ 4;
    gl_lds16(&kTb[(size_t)r0 * 512 + cs * 8],        &Ks[0][t * 8]);
    gl_lds16(&kTb[(size_t)(r0 + 32) * 512 + cs * 8], &Ks[0][t * 8 + 2048]);
    gl_lds16(&vb[(size_t)r0 * 1024 + cs * 8],        &Vs[0][t * 8]);
    gl_lds16(&vb[(size_t)(r0 + 32) * 1024 + cs * 8], &Vs[0][t * 8 + 2048]);
    __syncthreads();
    float lsum0 = 0.f, lsum1 = 0.f;
    f32x4 oacc[2][4] = {};
    ushort* Pw0 = &Ps[(w * 2 + 0) * 1152];
    ushort* Pw1 = &Ps[(w * 2 + 1) * 1152];
    int cur = 0;
    for (int j0 = 0; j0 < 512; j0 += 64) {
        if (j0 < 448) {
            int jn = j0 + 64, nx = cur ^ 1;
            gl_lds16(&kTb[(size_t)(jn + r0) * 512 + cs * 8],        &Ks[nx][t * 8]);
            gl_lds16(&kTb[(size_t)(jn + r0 + 32) * 512 + cs * 8],   &Ks[nx][t * 8 + 2048]);
            gl_lds16(&vb[(size_t)r0 * 1024 + jn + cs * 8],          &Vs[nx][t * 8]);
            gl_lds16(&vb[(size_t)(r0 + 32) * 1024 + jn + cs * 8],   &Vs[nx][t * 8 + 2048]);
        }
        const ushort* Kc = Ks[cur];
        const ushort* Vc = Vs[cur];
        f32x4 s0[4], s1[4];
#pragma unroll
        for (int jt = 0; jt < 4; ++jt) {
            int row = jt * 16 + l15;
            bf16x8 bk0 = *(const bf16x8*)&Kc[row * 64 + p0 * 8];
            bf16x8 bk1 = *(const bf16x8*)&Kc[row * 64 + p1 * 8];
            f32x4 a = {0.f, 0.f, 0.f, 0.f};
            a = __builtin_amdgcn_mfma_f32_16x16x32_bf16(bk0, aq[0][0], a, 0, 0, 0);
            a = __builtin_amdgcn_mfma_f32_16x16x32_bf16(bk1, aq[0][1], a, 0, 0, 0);
            s0[jt] = a;
            f32x4 c = {0.f, 0.f, 0.f, 0.f};
            c = __builtin_amdgcn_mfma_f32_16x16x32_bf16(bk0, aq[1][0], c, 0, 0, 0);
            c = __builtin_amdgcn_mfma_f32_16x16x32_bf16(bk1, aq[1][1], c, 0, 0, 0);
            s1[jt] = c;
        }
#pragma unroll
        for (int jt = 0; jt < 4; ++jt) {
            int o = l15 * 72 + jt * 16 + quad * 4;
            float e0 = EXP2F(s0[jt][0]), e1 = EXP2F(s0[jt][1]);
            float e2 = EXP2F(s0[jt][2]), e3 = EXP2F(s0[jt][3]);
            lsum0 += (e0 + e1) + (e2 + e3);
            *(uint*)&Pw0[o]     = cvt2(e0, e1);
            *(uint*)&Pw0[o + 2] = cvt2(e2, e3);
            float f0 = EXP2F(s1[jt][0]), f1 = EXP2F(s1[jt][1]);
            float f2 = EXP2F(s1[jt][2]), f3 = EXP2F(s1[jt][3]);
            lsum1 += (f0 + f1) + (f2 + f3);
            *(uint*)&Pw1[o]     = cvt2(f0, f1);
            *(uint*)&Pw1[o + 2] = cvt2(f2, f3);
        }
        __asm__ __volatile__("" ::: "memory");
        bf16x8 ap00 = *(const bf16x8*)&Pw0[l15 * 72 + quad * 8];
        bf16x8 ap01 = *(const bf16x8*)&Pw0[l15 * 72 + 32 + quad * 8];
        bf16x8 ap10 = *(const bf16x8*)&Pw1[l15 * 72 + quad * 8];
        bf16x8 ap11 = *(const bf16x8*)&Pw1[l15 * 72 + 32 + quad * 8];
#pragma unroll
        for (int ct = 0; ct < 4; ++ct) {
            int row = ct * 16 + l15;
            bf16x8 bv0 = *(const bf16x8*)&Vc[row * 64 + p0 * 8];
            bf16x8 bv1 = *(const bf16x8*)&Vc[row * 64 + p1 * 8];
            oacc[0][ct] = __builtin_amdgcn_mfma_f32_16x16x32_bf16(ap00, bv0, oacc[0][ct], 0, 0, 0);
            oacc[0][ct] = __builtin_amdgcn_mfma_f32_16x16x32_bf16(ap01, bv1, oacc[0][ct], 0, 0, 0);
            oacc[1][ct] = __builtin_amdgcn_mfma_f32_16x16x32_bf16(ap10, bv0, oacc[1][ct], 0, 0, 0);
            oacc[1][ct] = __builtin_amdgcn_mfma_f32_16x16x32_bf16(ap11, bv1, oacc[1][ct], 0, 0, 0);
        }
        __syncthreads();
        cur ^= 1;
    }
    // ---- per-row l partials (no normalization here) ----
    lsum0 += __shfl_xor(lsum0, 16); lsum0 += __shfl_xor(lsum0, 32);
    lsum1 += __shfl_xor(lsum1, 16); lsum1 += __shfl_xor(lsum1, 32);
    if (quad == 0) {
        lp[i0 + w * 16 + l15]      = lsum0;
        lp[i0 + 64 + w * 16 + l15] = lsum1;
    }
    // ---- epilogue: wave-private transpose of UNNORMALIZED O, uint4 stores --
#pragma unroll
    for (int rb = 0; rb < 2; ++rb) {
        ushort* Pw = (rb == 0) ? Pw0 : Pw1;
#pragma unroll
        for (int ct = 0; ct < 4; ++ct)
#pragma unroll
            for (int rr = 0; rr < 4; ++rr)
                Pw[(quad * 4 + rr) * 72 + ct * 16 + l15] = f2bf(oacc[rb][ct][rr]);
        __asm__ __volatile__("" ::: "memory");
#pragma unroll
        for (int p = 0; p < 2; ++p) {
            int row = p * 8 + (lane >> 3), ch = lane & 7;
            uint4 u = *(const uint4*)&Pw[row * 72 + ch * 8];
            *(uint4*)&opart[((size_t)b * 1024 + i0 + rb * 64 + w * 16 + row) * 256 + h * 64 + ch * 8] = u;
        }
    }
}

// ---------------------------------------------------------------------------
// K5: combine j-halves: ot = (O0 + O1) / (l0 + l1). Grid 2048 x 256,
// 8 bf16 elements per thread (uint4 loads/stores).
// ---------------------------------------------------------------------------
__global__ __launch_bounds__(256) void comb_k(
    const ushort* __restrict__ op0, const ushort* __restrict__ op1,
    const float* __restrict__ lpart, ushort* __restrict__ ot) {
    int e8 = (blockIdx.x * 256 + threadIdx.x) * 8;
    int b = e8 >> 18;
    int i = (e8 >> 8) & 1023;
    int c = e8 & 255;
    int bh = b * 4 + (c >> 6);
    float l = lpart[bh * 1024 + i] + lpart[65536 + bh * 1024 + i];
    float linv = 1.f / l;
    uint4 a = *(const uint4*)&op0[e8];
    uint4 d = *(const uint4*)&op1[e8];
    uint4 r;
    r.x = cvt2((bfl(a.x) + bfl(d.x)) * linv, (bfh(a.x) + bfh(d.x)) * linv);
    r.y = cvt2((bfl(a.y) + bfl(d.y)) * linv, (bfh(a.y) + bfh(d.y)) * linv);
    r.z = cvt2((bfl(a.z) + bfl(d.z)) * linv, (bfh(a.z) + bfh(d.z)) * linv);
    r.w = cvt2((bfl(a.w) + bfl(d.w)) * linv, (bfh(a.w) + bfh(d.w)) * linv);
    *(uint4*)&ot[e8] = r;
}

// ---------------------------------------------------------------------------
// K6: proj GEMM + bias + residual. 64(sp) x 128(chan) tiles -> 512 blocks
// (3/CU residency), BK=64 async dbuf. 4 waves: 2(chan) x 2(sp), acc[4][2].
// ---------------------------------------------------------------------------
__global__ __launch_bounds__(256, 3) void proj_k(
    const ushort* __restrict__ pwb, const ushort* __restrict__ ot,
    const float* __restrict__ pb, const float* __restrict__ x,
    float* __restrict__ out) {
    int b = blockIdx.z, cy = blockIdx.y, sx = blockIdx.x;
    __shared__ ushort SB[2][12288];  // [buf][ W 128*64 | X 64*64 ] = 48KB
    int t = threadIdx.x, lane = t & 63, w = t >> 6;
    int quad = lane >> 4, l15 = lane & 15;
    int wm = w >> 1, wn = w & 1;
    const ushort* wrow = pwb + (size_t)cy * 128 * 256;
    const ushort* xrow = ot + ((size_t)b * 1024 + sx * 64) * 256;
    int r0 = t >> 3;
    int cs = (t & 7) ^ (r0 & 7);
    int dst = t * 8;
#pragma unroll
    for (int ps = 0; ps < 4; ++ps)
        gl_lds16(&wrow[(size_t)(r0 + ps * 32) * 256 + cs * 8], &SB[0][ps * 2048 + dst]);
#pragma unroll
    for (int ps = 0; ps < 2; ++ps)
        gl_lds16(&xrow[(size_t)(r0 + ps * 32) * 256 + cs * 8], &SB[0][8192 + ps * 2048 + dst]);
    __syncthreads();
    int p0 = quad ^ (l15 & 7);
    f32x4 acc[4][2] = {};
    int cur = 0;
    for (int ki = 0; ki < 4; ++ki) {
        if (ki < 3) {
            int k0 = (ki + 1) * 64, nx = cur ^ 1;
#pragma unroll
            for (int ps = 0; ps < 4; ++ps)
                gl_lds16(&wrow[(size_t)(r0 + ps * 32) * 256 + k0 + cs * 8], &SB[nx][ps * 2048 + dst]);
#pragma unroll
            for (int ps = 0; ps < 2; ++ps)
                gl_lds16(&xrow[(size_t)(r0 + ps * 32) * 256 + k0 + cs * 8], &SB[nx][8192 + ps * 2048 + dst]);
        }
        const ushort* Wc = &SB[cur][0];
        const ushort* Xc = &SB[cur][8192];
#pragma unroll
        for (int kk = 0; kk < 2; ++kk) {
            int sl = p0 ^ (kk * 4);
            bf16x8 fa[4], fb[2];
#pragma unroll
            for (int mi = 0; mi < 4; ++mi)
                fa[mi] = *(const bf16x8*)&Wc[(wm * 64 + mi * 16 + l15) * 64 + sl * 8];
#pragma unroll
            for (int ni = 0; ni < 2; ++ni)
                fb[ni] = *(const bf16x8*)&Xc[(wn * 32 + ni * 16 + l15) * 64 + sl * 8];
#pragma unroll
            for (int mi = 0; mi < 4; ++mi)
#pragma unroll
                for (int ni = 0; ni < 2; ++ni)
                    acc[mi][ni] = __builtin_amdgcn_mfma_f32_16x16x32_bf16(
                        fa[mi], fb[ni], acc[mi][ni], 0, 0, 0);
        }
        __syncthreads();
        cur ^= 1;
    }
#pragma unroll
    for (int mi = 0; mi < 4; ++mi)
#pragma unroll
        for (int rr = 0; rr < 4; ++rr) {
            int chan = cy * 128 + wm * 64 + mi * 16 + quad * 4 + rr;
            float bias = pb[chan];
#pragma unroll
            for (int ni = 0; ni < 2; ++ni) {
                int sp = sx * 64 + wn * 32 + ni * 16 + l15;
                size_t o = ((size_t)(b * 256 + chan)) * 1024 + sp;
                out[o] = acc[mi][ni][rr] + bias + x[o];
            }
        }
}

// ---------------------------------------------------------------------------
extern "C" void kernel_launch(void* const* d_in, const int* in_sizes, int n_in,
                              void* d_out, int out_size, void* d_ws, size_t ws_size,
                              hipStream_t stream) {
    const float* x    = (const float*)d_in[0];
    const float* nw   = (const float*)d_in[1];
    const float* nb   = (const float*)d_in[2];
    const float* qkvw = (const float*)d_in[3];
    const float* qkvb = (const float*)d_in[4];
    const float* pw   = (const float*)d_in[5];
    const float* pb   = (const float*)d_in[6];
    float* out = (float*)d_out;

    // Workspace (~34.6 MB): pstats 4KB | lpart 512KB | xt | wqb | pwb | qkT | vbuf
    // Aliases: opart0 = xt (free after qkv); opart1 = d_out (rewritten by proj);
    // ot = vbuf region (V dead after attn).
    float* pstats = (float*)d_ws;
    float* lpart  = (float*)((char*)d_ws + 4096);            // 2*65536 f32
    ushort* base = (ushort*)((char*)d_ws + 4096 + 524288);
    ushort* xt   = base;                          // 16*1024*256
    ushort* wqb  = xt + (size_t)16 * 1024 * 256;  // 768*256
    ushort* pwb  = wqb + 768 * 256;               // 256*256
    ushort* qkT  = pwb + 256 * 256;               // 16*1024*512
    ushort* vbuf = qkT + (size_t)16 * 1024 * 512; // 16*256*1024
    ushort* op0  = xt;                            // reuse
    ushort* op1  = (ushort*)d_out;                // reuse (proj rewrites d_out)
    ushort* ot   = vbuf;                          // reuse (V consumed by attn)

    pre_k<<<dim3(768), dim3(256), 0, stream>>>(x, qkvw, pw, pstats, wqb, pwb);
    norm_t_k<<<dim3(16, 4, Bc), dim3(256), 0, stream>>>(x, pstats, nw, nb, xt);
    qkv_gemm_k<<<dim3(8, 6, Bc), dim3(256), 0, stream>>>(wqb, xt, qkvb, qkT, vbuf);
    attn_k<<<dim3(8, 64, 2), dim3(256), 0, stream>>>(qkT, vbuf, op0, op1, lpart);
    comb_k<<<dim3(2048), dim3(256), 0, stream>>>(op0, op1, lpart, ot);
    proj_k<<<dim3(16, 2, Bc), dim3(256), 0, stream>>>(pwb, ot, pb, x, out);
}

// Round 11
// 131.664 us; speedup vs baseline: 1.5097x; 1.0880x over previous
//
#include <hip/hip_runtime.h>
#include <math.h>

typedef unsigned short ushort;
typedef unsigned int uint;
typedef __attribute__((ext_vector_type(8))) short bf16x8;
typedef __attribute__((ext_vector_type(4))) float f32x4;

constexpr int Bc  = 16;
constexpr float EPSc = 1e-5f;
constexpr float QSC  = 0.18033688f;  // 0.125 * log2(e): softmax exp -> exp2

__device__ inline ushort f2bf(float f) {
    uint u = __float_as_uint(f);
    uint r = (u + 0x7fffu + ((u >> 16) & 1u)) >> 16;
    return (ushort)r;
}
__device__ inline uint pack2(float a, float b) {
    return (uint)f2bf(a) | ((uint)f2bf(b) << 16);
}
__device__ __forceinline__ uint cvt2(float a, float b) {
#if __has_builtin(__builtin_amdgcn_cvt_pk_bf16_f32)
    auto v = __builtin_amdgcn_cvt_pk_bf16_f32(a, b);
    uint u; __builtin_memcpy(&u, &v, 4); return u;
#else
    return pack2(a, b);
#endif
}
#if __has_builtin(__builtin_amdgcn_exp2f)
#define EXP2F(x) __builtin_amdgcn_exp2f(x)
#else
#define EXP2F(x) __expf((x) * 0.69314718f)
#endif
__device__ __forceinline__ void gl_lds16(const ushort* g, ushort* l) {
    __builtin_amdgcn_global_load_lds(
        (const __attribute__((address_space(1))) void*)g,
        (__attribute__((address_space(3))) void*)l, 16, 0, 0);
}

// ---------------------------------------------------------------------------
// K1: merged. Blocks 0..511: per-(b,g) partial sums. 512..767: weight cvt
// (Q rows pre-scaled by QSC).
// ---------------------------------------------------------------------------
__global__ __launch_bounds__(256) void pre_k(
    const float* __restrict__ x, const float* __restrict__ qkvw,
    const float* __restrict__ pw, float* __restrict__ pstats,
    ushort* __restrict__ wqb, ushort* __restrict__ pwb) {
    int blk = blockIdx.x;
    if (blk < 512) {
        int bg = blk >> 2, part = blk & 3;
        const float4* p = (const float4*)(x + (size_t)bg * 32768 + part * 8192);
        float s = 0.f, s2 = 0.f;
        for (int i = threadIdx.x; i < 2048; i += 256) {
            float4 v = p[i];
            s += v.x + v.y + v.z + v.w;
            s2 += v.x*v.x + v.y*v.y + v.z*v.z + v.w*v.w;
        }
        __shared__ float rs[256], rq[256];
        rs[threadIdx.x] = s; rq[threadIdx.x] = s2;
        __syncthreads();
        for (int off = 128; off > 0; off >>= 1) {
            if (threadIdx.x < (unsigned)off) {
                rs[threadIdx.x] += rs[threadIdx.x + off];
                rq[threadIdx.x] += rq[threadIdx.x + off];
            }
            __syncthreads();
        }
        if (threadIdx.x == 0) {
            pstats[blk * 2]     = rs[0];
            pstats[blk * 2 + 1] = rq[0];
        }
    } else {
        int idx = ((blk - 512) * 256 + threadIdx.x) * 4;
        if (idx < 196608) {
            int row = idx >> 8;
            float sc = (row < 256) ? QSC : 1.f;
            float4 v = *(const float4*)&qkvw[idx];
            uint2 u; u.x = pack2(v.x * sc, v.y * sc); u.y = pack2(v.z * sc, v.w * sc);
            *(uint2*)&wqb[idx] = u;
        } else {
            int j = idx - 196608;
            float4 v = *(const float4*)&pw[j];
            uint2 u; u.x = pack2(v.x, v.y); u.y = pack2(v.z, v.w);
            *(uint2*)&pwb[j] = u;
        }
    }
}

// ---------------------------------------------------------------------------
// K2: GroupNorm (finalize partial stats) + cast + transpose:
// x[b][c][n] -> xt[b][n][c] bf16. Grid (16, 4, 16).
// ---------------------------------------------------------------------------
__global__ __launch_bounds__(256) void norm_t_k(
    const float* __restrict__ x, const float* __restrict__ pstats,
    const float* __restrict__ nw, const float* __restrict__ nb,
    ushort* __restrict__ xt) {
    int b = blockIdx.z, ct = blockIdx.y, nt = blockIdx.x;
    __shared__ ushort T[64 * 72];
    int t = threadIdx.x;
    int nn4 = (t & 15) * 4;
#pragma unroll
    for (int p = 0; p < 4; ++p) {
        int cl = (t >> 4) + p * 16;
        int c = ct * 64 + cl;
        int g = c >> 5;
        int base = (b * 8 + g) * 8;
        float s  = (pstats[base] + pstats[base+2]) + (pstats[base+4] + pstats[base+6]);
        float s2 = (pstats[base+1] + pstats[base+3]) + (pstats[base+5] + pstats[base+7]);
        float inv_n = 1.f / 32768.f;
        float mean = s * inv_n;
        float var  = s2 * inv_n - mean * mean;
        float inv  = rsqrtf(var + EPSc);
        float sw = inv * nw[c];
        float sb = nb[c] - mean * sw;
        float4 v = *(const float4*)&x[((size_t)(b * 256 + c)) * 1024 + nt * 64 + nn4];
        T[(nn4 + 0) * 72 + cl] = f2bf(v.x * sw + sb);
        T[(nn4 + 1) * 72 + cl] = f2bf(v.y * sw + sb);
        T[(nn4 + 2) * 72 + cl] = f2bf(v.z * sw + sb);
        T[(nn4 + 3) * 72 + cl] = f2bf(v.w * sw + sb);
    }
    __syncthreads();
#pragma unroll
    for (int p = 0; p < 4; ++p) {
        int nn = (t >> 4) + p * 16;
        int c4 = (t & 15) * 4;
        uint2 w = *(const uint2*)&T[nn * 72 + c4];
        *(uint2*)&xt[((size_t)b * 1024 + nt * 64 + nn) * 256 + ct * 64 + c4] = w;
    }
}

// ---------------------------------------------------------------------------
// K3: qkv GEMM (round-7 proven): BK=64 async dbuf, 1 barrier/iter.
// 128x128 tile, 4 waves. cy 0..3 -> qkT transposed; cy 4..5 -> vbuf natural.
// (Same-(b,sx) blocks already land on one XCD: id mod 8 = sx+48b mod 8.)
// ---------------------------------------------------------------------------
__global__ __launch_bounds__(256, 2) void qkv_gemm_k(
    const ushort* __restrict__ wq, const ushort* __restrict__ xt,
    const float* __restrict__ wb, ushort* __restrict__ qkT,
    ushort* __restrict__ vbuf) {
    int b = blockIdx.z, cy = blockIdx.y, sx = blockIdx.x;
    __shared__ ushort SB[2][2][128 * 64];
    int t = threadIdx.x, lane = t & 63, w = t >> 6;
    int quad = lane >> 4, l15 = lane & 15;
    int wm = w >> 1, wn = w & 1;
    const ushort* wrow = wq + (size_t)cy * 128 * 256;
    const ushort* xrow = xt + ((size_t)b * 1024 + sx * 128) * 256;
    bool tpath = (cy < 4);
    int r0 = t >> 3;
    int cs = (t & 7) ^ (r0 & 7);
    int dst = t * 8;
#pragma unroll
    for (int ps = 0; ps < 4; ++ps) {
        int r = r0 + ps * 32;
        gl_lds16(&wrow[(size_t)r * 256 + cs * 8], &SB[0][0][ps * 2048 + dst]);
        gl_lds16(&xrow[(size_t)r * 256 + cs * 8], &SB[0][1][ps * 2048 + dst]);
    }
    __syncthreads();
    int s0 = quad ^ (l15 & 7);
    f32x4 acc[4][4] = {};
    int cur = 0;
    for (int ki = 0; ki < 4; ++ki) {
        if (ki < 3) {
            int k0 = (ki + 1) * 64, nx = cur ^ 1;
#pragma unroll
            for (int ps = 0; ps < 4; ++ps) {
                int r = r0 + ps * 32;
                gl_lds16(&wrow[(size_t)r * 256 + k0 + cs * 8], &SB[nx][0][ps * 2048 + dst]);
                gl_lds16(&xrow[(size_t)r * 256 + k0 + cs * 8], &SB[nx][1][ps * 2048 + dst]);
            }
        }
        const ushort* Wc = SB[cur][0];
        const ushort* Xc = SB[cur][1];
        const ushort* Am = tpath ? Xc : Wc;
        const ushort* Bn = tpath ? Wc : Xc;
#pragma unroll
        for (int kk = 0; kk < 2; ++kk) {
            int sl = s0 ^ (kk * 4);
            bf16x8 fa[4], fb[4];
#pragma unroll
            for (int mi = 0; mi < 4; ++mi)
                fa[mi] = *(const bf16x8*)&Am[(wm * 64 + mi * 16 + l15) * 64 + sl * 8];
#pragma unroll
            for (int ni = 0; ni < 4; ++ni)
                fb[ni] = *(const bf16x8*)&Bn[(wn * 64 + ni * 16 + l15) * 64 + sl * 8];
#pragma unroll
            for (int mi = 0; mi < 4; ++mi)
#pragma unroll
                for (int ni = 0; ni < 4; ++ni)
                    acc[mi][ni] = __builtin_amdgcn_mfma_f32_16x16x32_bf16(
                        fa[mi], fb[ni], acc[mi][ni], 0, 0, 0);
        }
        __syncthreads();
        cur ^= 1;
    }
    __syncthreads();
    ushort* Tw = ((ushort*)SB) + w * (64 * 72);
    float bsc = (tpath && cy < 2) ? QSC : 1.f;
    if (tpath) {
#pragma unroll
        for (int ni = 0; ni < 4; ++ni) {
            float bias = wb[cy * 128 + wn * 64 + ni * 16 + l15] * bsc;
#pragma unroll
            for (int mi = 0; mi < 4; ++mi)
#pragma unroll
                for (int rr = 0; rr < 4; ++rr)
                    Tw[(mi * 16 + quad * 4 + rr) * 72 + ni * 16 + l15] =
                        f2bf(acc[mi][ni][rr] + bias);
        }
    } else {
#pragma unroll
        for (int mi = 0; mi < 4; ++mi)
#pragma unroll
            for (int rr = 0; rr < 4; ++rr) {
                float bias = wb[cy * 128 + wm * 64 + mi * 16 + quad * 4 + rr];
#pragma unroll
                for (int ni = 0; ni < 4; ++ni)
                    Tw[(mi * 16 + quad * 4 + rr) * 72 + ni * 16 + l15] =
                        f2bf(acc[mi][ni][rr] + bias);
            }
    }
    __asm__ __volatile__("" ::: "memory");
    int row8 = lane >> 3, ch = lane & 7;
#pragma unroll
    for (int p = 0; p < 8; ++p) {
        int row = p * 8 + row8;
        uint4 u = *(const uint4*)&Tw[row * 72 + ch * 8];
        if (tpath) {
            int sp = sx * 128 + wm * 64 + row;
            *(uint4*)&qkT[((size_t)b * 1024 + sp) * 512 + cy * 128 + wn * 64 + ch * 8] = u;
        } else {
            int chanloc = (cy - 4) * 128 + wm * 64 + row;
            *(uint4*)&vbuf[((size_t)b * 256 + chanloc) * 1024 + sx * 128 + wn * 64 + ch * 8] = u;
        }
    }
}

// ---------------------------------------------------------------------------
// K4: flash attention, 128-row i-tiles, XCD-AFFINE grid: bh = blockIdx.x,
// i-tile = blockIdx.y, grid (64, 8). Same-bh blocks (sharing the 256KB K/V
// stream) get consecutive-mod-8 linear IDs -> same XCD -> K/V served from
// that XCD's L2 after first fetch. Structure otherwise round-7.
// ---------------------------------------------------------------------------
__global__ __launch_bounds__(256, 3) void attn_k(
    const ushort* __restrict__ qkT, const ushort* __restrict__ vbuf,
    ushort* __restrict__ ot) {
    int bh = blockIdx.x;
    int i0 = blockIdx.y * 128;
    int b = bh >> 2, h = bh & 3;
    const ushort* qTb = qkT + (size_t)b * 1024 * 512 + h * 64;
    const ushort* kTb = qTb + 256;
    const ushort* vb  = vbuf + ((size_t)(b * 256 + h * 64)) * 1024;
    __shared__ ushort Ks[2][4096], Vs[2][4096];  // [row][chunk^(row&7)], stride 64
    __shared__ ushort Ps[8 * 1152];              // [wave][rb] 16x64 pad 72
    __shared__ float  Lx[128];
    int t = threadIdx.x, lane = t & 63, w = t >> 6;
    int quad = lane >> 4, l15 = lane & 15;
    bf16x8 aq[2][2];
#pragma unroll
    for (int rb = 0; rb < 2; ++rb) {
        const ushort* qr = &qTb[(size_t)(i0 + rb * 64 + w * 16 + l15) * 512];
        aq[rb][0] = *(const bf16x8*)&qr[quad * 8];
        aq[rb][1] = *(const bf16x8*)&qr[32 + quad * 8];
    }
    int r0 = t >> 3;
    int cs = (t & 7) ^ (r0 & 7);
    int p0 = quad ^ (l15 & 7);
    int p1 = p0 ^ 4;
    gl_lds16(&kTb[(size_t)r0 * 512 + cs * 8],        &Ks[0][t * 8]);
    gl_lds16(&kTb[(size_t)(r0 + 32) * 512 + cs * 8], &Ks[0][t * 8 + 2048]);
    gl_lds16(&vb[(size_t)r0 * 1024 + cs * 8],        &Vs[0][t * 8]);
    gl_lds16(&vb[(size_t)(r0 + 32) * 1024 + cs * 8], &Vs[0][t * 8 + 2048]);
    __syncthreads();
    float lsum0 = 0.f, lsum1 = 0.f;
    f32x4 oacc[2][4] = {};
    ushort* Pw0 = &Ps[(w * 2 + 0) * 1152];
    ushort* Pw1 = &Ps[(w * 2 + 1) * 1152];
    int cur = 0;
    for (int j0 = 0; j0 < 1024; j0 += 64) {
        if (j0 < 960) {
            int jn = j0 + 64, nx = cur ^ 1;
            gl_lds16(&kTb[(size_t)(jn + r0) * 512 + cs * 8],        &Ks[nx][t * 8]);
            gl_lds16(&kTb[(size_t)(jn + r0 + 32) * 512 + cs * 8],   &Ks[nx][t * 8 + 2048]);
            gl_lds16(&vb[(size_t)r0 * 1024 + jn + cs * 8],          &Vs[nx][t * 8]);
            gl_lds16(&vb[(size_t)(r0 + 32) * 1024 + jn + cs * 8],   &Vs[nx][t * 8 + 2048]);
        }
        const ushort* Kc = Ks[cur];
        const ushort* Vc = Vs[cur];
        f32x4 s0[4], s1[4];
#pragma unroll
        for (int jt = 0; jt < 4; ++jt) {
            int row = jt * 16 + l15;
            bf16x8 bk0 = *(const bf16x8*)&Kc[row * 64 + p0 * 8];
            bf16x8 bk1 = *(const bf16x8*)&Kc[row * 64 + p1 * 8];
            f32x4 a = {0.f, 0.f, 0.f, 0.f};
            a = __builtin_amdgcn_mfma_f32_16x16x32_bf16(bk0, aq[0][0], a, 0, 0, 0);
            a = __builtin_amdgcn_mfma_f32_16x16x32_bf16(bk1, aq[0][1], a, 0, 0, 0);
            s0[jt] = a;
            f32x4 c = {0.f, 0.f, 0.f, 0.f};
            c = __builtin_amdgcn_mfma_f32_16x16x32_bf16(bk0, aq[1][0], c, 0, 0, 0);
            c = __builtin_amdgcn_mfma_f32_16x16x32_bf16(bk1, aq[1][1], c, 0, 0, 0);
            s1[jt] = c;
        }
#pragma unroll
        for (int jt = 0; jt < 4; ++jt) {
            int o = l15 * 72 + jt * 16 + quad * 4;
            float e0 = EXP2F(s0[jt][0]), e1 = EXP2F(s0[jt][1]);
            float e2 = EXP2F(s0[jt][2]), e3 = EXP2F(s0[jt][3]);
            lsum0 += (e0 + e1) + (e2 + e3);
            *(uint*)&Pw0[o]     = cvt2(e0, e1);
            *(uint*)&Pw0[o + 2] = cvt2(e2, e3);
            float f0 = EXP2F(s1[jt][0]), f1 = EXP2F(s1[jt][1]);
            float f2 = EXP2F(s1[jt][2]), f3 = EXP2F(s1[jt][3]);
            lsum1 += (f0 + f1) + (f2 + f3);
            *(uint*)&Pw1[o]     = cvt2(f0, f1);
            *(uint*)&Pw1[o + 2] = cvt2(f2, f3);
        }
        __asm__ __volatile__("" ::: "memory");
        bf16x8 ap00 = *(const bf16x8*)&Pw0[l15 * 72 + quad * 8];
        bf16x8 ap01 = *(const bf16x8*)&Pw0[l15 * 72 + 32 + quad * 8];
        bf16x8 ap10 = *(const bf16x8*)&Pw1[l15 * 72 + quad * 8];
        bf16x8 ap11 = *(const bf16x8*)&Pw1[l15 * 72 + 32 + quad * 8];
#pragma unroll
        for (int ct = 0; ct < 4; ++ct) {
            int row = ct * 16 + l15;
            bf16x8 bv0 = *(const bf16x8*)&Vc[row * 64 + p0 * 8];
            bf16x8 bv1 = *(const bf16x8*)&Vc[row * 64 + p1 * 8];
            oacc[0][ct] = __builtin_amdgcn_mfma_f32_16x16x32_bf16(ap00, bv0, oacc[0][ct], 0, 0, 0);
            oacc[0][ct] = __builtin_amdgcn_mfma_f32_16x16x32_bf16(ap01, bv1, oacc[0][ct], 0, 0, 0);
            oacc[1][ct] = __builtin_amdgcn_mfma_f32_16x16x32_bf16(ap10, bv0, oacc[1][ct], 0, 0, 0);
            oacc[1][ct] = __builtin_amdgcn_mfma_f32_16x16x32_bf16(ap11, bv1, oacc[1][ct], 0, 0, 0);
        }
        __syncthreads();
        cur ^= 1;
    }
    lsum0 += __shfl_xor(lsum0, 16); lsum0 += __shfl_xor(lsum0, 32);
    lsum1 += __shfl_xor(lsum1, 16); lsum1 += __shfl_xor(lsum1, 32);
    if (quad == 0) {
        Lx[w * 16 + l15]      = lsum0;
        Lx[64 + w * 16 + l15] = lsum1;
    }
    __asm__ __volatile__("" ::: "memory");
#pragma unroll
    for (int rb = 0; rb < 2; ++rb) {
        float4 lv = *(const float4*)&Lx[rb * 64 + w * 16 + quad * 4];
        float linv[4] = {1.f / lv.x, 1.f / lv.y, 1.f / lv.z, 1.f / lv.w};
        ushort* Pw = (rb == 0) ? Pw0 : Pw1;
#pragma unroll
        for (int ct = 0; ct < 4; ++ct)
#pragma unroll
            for (int rr = 0; rr < 4; ++rr)
                Pw[(quad * 4 + rr) * 72 + ct * 16 + l15] = f2bf(oacc[rb][ct][rr] * linv[rr]);
        __asm__ __volatile__("" ::: "memory");
#pragma unroll
        for (int p = 0; p < 2; ++p) {
            int row = p * 8 + (lane >> 3), ch = lane & 7;
            uint4 u = *(const uint4*)&Pw[row * 72 + ch * 8];
            *(uint4*)&ot[((size_t)b * 1024 + i0 + rb * 64 + w * 16 + row) * 256 + h * 64 + ch * 8] = u;
        }
    }
}

// ---------------------------------------------------------------------------
// K5: proj GEMM + bias + residual. 64(sp) x 128(chan) tiles -> 512 blocks
// (2/CU), BK=64 async dbuf, 48KB LDS. 4 waves: 2(chan) x 2(sp), acc[4][2].
// ---------------------------------------------------------------------------
__global__ __launch_bounds__(256, 3) void proj_k(
    const ushort* __restrict__ pwb, const ushort* __restrict__ ot,
    const float* __restrict__ pb, const float* __restrict__ x,
    float* __restrict__ out) {
    int b = blockIdx.z, cy = blockIdx.y, sx = blockIdx.x;
    __shared__ ushort SB[2][12288];  // [buf][ W 128*64 | X 64*64 ] = 48KB
    int t = threadIdx.x, lane = t & 63, w = t >> 6;
    int quad = lane >> 4, l15 = lane & 15;
    int wm = w >> 1, wn = w & 1;
    const ushort* wrow = pwb + (size_t)cy * 128 * 256;
    const ushort* xrow = ot + ((size_t)b * 1024 + sx * 64) * 256;
    int r0 = t >> 3;
    int cs = (t & 7) ^ (r0 & 7);
    int dst = t * 8;
#pragma unroll
    for (int ps = 0; ps < 4; ++ps)
        gl_lds16(&wrow[(size_t)(r0 + ps * 32) * 256 + cs * 8], &SB[0][ps * 2048 + dst]);
#pragma unroll
    for (int ps = 0; ps < 2; ++ps)
        gl_lds16(&xrow[(size_t)(r0 + ps * 32) * 256 + cs * 8], &SB[0][8192 + ps * 2048 + dst]);
    __syncthreads();
    int p0 = quad ^ (l15 & 7);
    f32x4 acc[4][2] = {};
    int cur = 0;
    for (int ki = 0; ki < 4; ++ki) {
        if (ki < 3) {
            int k0 = (ki + 1) * 64, nx = cur ^ 1;
#pragma unroll
            for (int ps = 0; ps < 4; ++ps)
                gl_lds16(&wrow[(size_t)(r0 + ps * 32) * 256 + k0 + cs * 8], &SB[nx][ps * 2048 + dst]);
#pragma unroll
            for (int ps = 0; ps < 2; ++ps)
                gl_lds16(&xrow[(size_t)(r0 + ps * 32) * 256 + k0 + cs * 8], &SB[nx][8192 + ps * 2048 + dst]);
        }
        const ushort* Wc = &SB[cur][0];
        const ushort* Xc = &SB[cur][8192];
#pragma unroll
        for (int kk = 0; kk < 2; ++kk) {
            int sl = p0 ^ (kk * 4);
            bf16x8 fa[4], fb[2];
#pragma unroll
            for (int mi = 0; mi < 4; ++mi)
                fa[mi] = *(const bf16x8*)&Wc[(wm * 64 + mi * 16 + l15) * 64 + sl * 8];
#pragma unroll
            for (int ni = 0; ni < 2; ++ni)
                fb[ni] = *(const bf16x8*)&Xc[(wn * 32 + ni * 16 + l15) * 64 + sl * 8];
#pragma unroll
            for (int mi = 0; mi < 4; ++mi)
#pragma unroll
                for (int ni = 0; ni < 2; ++ni)
                    acc[mi][ni] = __builtin_amdgcn_mfma_f32_16x16x32_bf16(
                        fa[mi], fb[ni], acc[mi][ni], 0, 0, 0);
        }
        __syncthreads();
        cur ^= 1;
    }
#pragma unroll
    for (int mi = 0; mi < 4; ++mi)
#pragma unroll
        for (int rr = 0; rr < 4; ++rr) {
            int chan = cy * 128 + wm * 64 + mi * 16 + quad * 4 + rr;
            float bias = pb[chan];
#pragma unroll
            for (int ni = 0; ni < 2; ++ni) {
                int sp = sx * 64 + wn * 32 + ni * 16 + l15;
                size_t o = ((size_t)(b * 256 + chan)) * 1024 + sp;
                out[o] = acc[mi][ni][rr] + bias + x[o];
            }
        }
}

// ---------------------------------------------------------------------------
extern "C" void kernel_launch(void* const* d_in, const int* in_sizes, int n_in,
                              void* d_out, int out_size, void* d_ws, size_t ws_size,
                              hipStream_t stream) {
    const float* x    = (const float*)d_in[0];
    const float* nw   = (const float*)d_in[1];
    const float* nb   = (const float*)d_in[2];
    const float* qkvw = (const float*)d_in[3];
    const float* qkvb = (const float*)d_in[4];
    const float* pw   = (const float*)d_in[5];
    const float* pb   = (const float*)d_in[6];
    float* out = (float*)d_out;

    // Workspace (~34 MB): pstats | xt | wqb | pwb | qkT | vbuf; ot aliases xt.
    float* pstats = (float*)d_ws;
    ushort* base = (ushort*)((char*)d_ws + 4096);
    ushort* xt   = base;                          // 16*1024*256
    ushort* wqb  = xt + (size_t)16 * 1024 * 256;  // 768*256
    ushort* pwb  = wqb + 768 * 256;               // 256*256
    ushort* qkT  = pwb + 256 * 256;               // 16*1024*512
    ushort* vbuf = qkT + (size_t)16 * 1024 * 512; // 16*256*1024
    ushort* ot   = xt;                            // reuse

    pre_k<<<dim3(768), dim3(256), 0, stream>>>(x, qkvw, pw, pstats, wqb, pwb);
    norm_t_k<<<dim3(16, 4, Bc), dim3(256), 0, stream>>>(x, pstats, nw, nb, xt);
    qkv_gemm_k<<<dim3(8, 6, Bc), dim3(256), 0, stream>>>(wqb, xt, qkvb, qkT, vbuf);
    attn_k<<<dim3(64, 8), dim3(256), 0, stream>>>(qkT, vbuf, ot);
    proj_k<<<dim3(16, 2, Bc), dim3(256), 0, stream>>>(pwb, ot, pb, x, out);
}